// Round 1
// 782.834 us; speedup vs baseline: 1.0429x; 1.0429x over previous
//
#include <hip/hip_runtime.h>

#define BB 8
#define TT 16
#define CIN 32
#define HID 64
#define HH 64
#define WW 64
#define EPS 1e-3f
#define NEG_SLOPE 0.01f

typedef short s16x8 __attribute__((ext_vector_type(8)));
typedef __bf16 bfx8 __attribute__((ext_vector_type(8)));
typedef float fx4 __attribute__((ext_vector_type(4)));

__device__ __forceinline__ unsigned short f2bf(float f) {
    union { float f; unsigned u; } v; v.f = f;
    unsigned r = v.u + 0x7fffu + ((v.u >> 16) & 1u);
    return (unsigned short)(r >> 16);
}
__device__ __forceinline__ float bf2f(unsigned short b) {
    union { unsigned u; float f; } v; v.u = ((unsigned)b) << 16;
    return v.f;
}
__device__ __forceinline__ float tanh_fast(float x) {
    x = fminf(fmaxf(x, -15.f), 15.f);
    float e = __expf(-2.f * x);
    return (1.f - e) / (1.f + e);
}
static __device__ __forceinline__ bfx8 as_bf(s16x8 v) {
    union { s16x8 s; bfx8 b; } u; u.s = v; return u.b;
}

// x (NCHW fp32) -> xcl [b][t][y*64+x][32] bf16
__global__ __launch_bounds__(256) void x2bf(const float* __restrict__ x,
                                            unsigned short* __restrict__ xcl) {
    __shared__ float s[32][65];
    int y = blockIdx.x, t = blockIdx.y, b = blockIdx.z;
    int tid = threadIdx.x;
    const float* src = x + (((size_t)(b * TT + t) * CIN) * HH + y) * WW;
#pragma unroll
    for (int k = 0; k < 8; ++k) {
        int idx = tid + k * 256;
        int c = idx >> 6, xx = idx & 63;
        s[c][xx] = src[(size_t)c * HH * WW + xx];
    }
    __syncthreads();
    int xx = tid >> 2, c0 = (tid & 3) * 8;
    unsigned short tmp[8];
#pragma unroll
    for (int j = 0; j < 8; ++j) tmp[j] = f2bf(s[c0 + j][xx]);
    unsigned short* dst = xcl + (((size_t)(b * TT + t) * 4096) + y * 64 + xx) * 32 + c0;
    *(s16x8*)dst = *(s16x8*)tmp;
}

// w [256 oc][96 ch][3][3] fp32 -> wpkb [tap(9)][k8(12)][n(256)][k7(8)] bf16
// n-mapping: gate=(n>>4)&3, hid=(n>>6)*16+(n&15), oc=gate*64+hid
// This makes the per-wave B-fragment load (16 consecutive n x 16B) coalesced.
__global__ __launch_bounds__(256) void pack_wb(const float* __restrict__ w,
                                               unsigned short* __restrict__ wpkb) {
    int idx = blockIdx.x * 256 + threadIdx.x;
    if (idx >= 256 * 864) return;
    int k7 = idx & 7;
    int j = idx >> 3;
    int n = j & 255;
    int kk = j >> 8;          // tap*12 + k8
    int k8 = kk % 12;
    int tap = kk / 12;
    int ks = k8 * 8 + k7;     // 0..95 channel index of concat [x(32), h(64)]
    int gate = (n >> 4) & 3;
    int hid  = (n >> 6) * 16 + (n & 15);
    int oc   = gate * 64 + hid;
    wpkb[idx] = f2bf(w[((size_t)oc * 96 + ks) * 9 + tap]);
}

// X contribution: A-fragments gathered directly from xcl (L2-resident, the
// 64-lane access covers 16 full 64B lines -> fully coalesced). No LDS, no bar.
__device__ __forceinline__ void do_taps_x(const unsigned short* __restrict__ xcl_bt,
                                          const unsigned short* __restrict__ wpkb,
                                          fx4 (&acc)[4][4],
                                          int y0, int lane15, int kq, int w4) {
#pragma unroll
    for (int tap = 0; tap < 9; ++tap) {
        const int ky = tap / 3, kx = tap % 3;
        const int iy = y0 + ky - 1;            // block-uniform
        bfx8 bf[4];
#pragma unroll
        for (int g = 0; g < 4; ++g) {
            int n = (4 * w4 + g) * 16 + lane15;
            bf[g] = *(const bfx8*)(wpkb + ((size_t)((tap * 12 + kq) * 256 + n)) * 8);
        }
        if (iy >= 0 && iy < 64) {
            bfx8 af[4];
#pragma unroll
            for (int m = 0; m < 4; ++m) {
                int ix = m * 16 + lane15 + kx - 1;
                s16x8 v = (s16x8)0;
                if (ix >= 0 && ix < 64)
                    v = *(const s16x8*)(xcl_bt + ((size_t)iy * 64 + ix) * 32 + kq * 8);
                af[m] = as_bf(v);
            }
#pragma unroll
            for (int m = 0; m < 4; ++m)
#pragma unroll
                for (int g = 0; g < 4; ++g)
                    acc[m][g] = __builtin_amdgcn_mfma_f32_16x16x32_bf16(af[m], bf[g], acc[m][g], 0, 0, 0);
        }
    }
}

// H contribution: all 128 h-channels (hi/lo pairs) staged at stride 136.
// Sections within a pixel record: [hi j<32 @0][lo j<32 @32][hi j>=32 @64][lo j>=32 @96].
__device__ __forceinline__ void do_taps_h(const unsigned short* s_a,
                                          const unsigned short* __restrict__ wpkb,
                                          fx4 (&acc)[4][4],
                                          int lane15, int kq, int w4) {
#pragma unroll
    for (int tap = 0; tap < 9; ++tap) {
        const int ky = tap / 3, kx = tap % 3;
        bfx8 bfA[4], bfB[4];
#pragma unroll
        for (int g = 0; g < 4; ++g) {
            int n = (4 * w4 + g) * 16 + lane15;
            bfA[g] = *(const bfx8*)(wpkb + ((size_t)((tap * 12 + 4 + kq) * 256 + n)) * 8);
            bfB[g] = *(const bfx8*)(wpkb + ((size_t)((tap * 12 + 8 + kq) * 256 + n)) * 8);
        }
#pragma unroll
        for (int sect = 0; sect < 4; ++sect) {
            bfx8 af[4];
#pragma unroll
            for (int m = 0; m < 4; ++m) {
                int col = m * 16 + lane15 + kx;
                af[m] = *(const bfx8*)(s_a + (ky * 66 + col) * 136 + sect * 32 + kq * 8);
            }
#pragma unroll
            for (int m = 0; m < 4; ++m)
#pragma unroll
                for (int g = 0; g < 4; ++g)
                    acc[m][g] = __builtin_amdgcn_mfma_f32_16x16x32_bf16(
                        af[m], (sect < 2) ? bfA[g] : bfB[g], acc[m][g], 0, 0, 0);
        }
    }
}

// One timestep. grid (64 rows, 8 b), 256 thr (4 waves), 2 blocks/CU.
// M=64 pixels (row y0), N=256 (4 gates x 64 hid). One barrier per step.
__global__ __launch_bounds__(256, 2) void lstm_step(
    const unsigned short* __restrict__ xcl,
    const unsigned short* __restrict__ wpkb,
    const float* __restrict__ bias,
    const unsigned short* __restrict__ h_in,
    unsigned short* __restrict__ h_out,
    float* __restrict__ c_ws,
    float* __restrict__ out,
    float* __restrict__ partial,
    int t) {
    const int y0 = blockIdx.x, b = blockIdx.y;
    const int tid = threadIdx.x;
    const int lane15 = tid & 15;
    const int kq = (tid >> 4) & 3;
    const int w4 = tid >> 6;

    __shared__ __align__(16) unsigned short s_a[3 * 66 * 136];   // 53,856 B

    fx4 acc[4][4];
#pragma unroll
    for (int m = 0; m < 4; ++m)
#pragma unroll
        for (int g = 0; g < 4; ++g) acc[m][g] = (fx4)0.f;

    // ---- stage h tile: 3 rows x 66 x 128ch @ stride 136 (issued first) ----
    for (int u = tid; u < 3 * 66 * 16; u += 256) {
        int unit = u & 15, pix = u >> 4;
        int col = pix % 66, r = pix / 66;
        int iy = y0 + r - 1, ix = col - 1;
        s16x8 v = (s16x8)0;
        if (iy >= 0 && iy < 64 && ix >= 0 && ix < 64)
            v = *(const s16x8*)(h_in + ((size_t)(b * 64 + iy) * 64 + ix) * 128 + unit * 8);
        *(s16x8*)(s_a + (r * 66 + col) * 136 + unit * 8) = v;
    }

    // ---- X taps while other waves/blocks stage (no LDS dependency) ----
    const unsigned short* xcl_bt = xcl + (size_t)(b * TT + t) * 4096 * 32;
    do_taps_x(xcl_bt, wpkb, acc, y0, lane15, kq, w4);

    __syncthreads();

    // ---- H taps from LDS ----
    do_taps_h(s_a, wpkb, acc, lane15, kq, w4);

    // ---- Epilogue: LSTM gate math; lane owns hid = 16*w4 + lane15 ----
    const int hid = w4 * 16 + lane15;
    const float bi = bias[0 * 64 + hid], bff = bias[1 * 64 + hid];
    const float bo = bias[2 * 64 + hid], bg = bias[3 * 64 + hid];
    const int chh = (hid < 32) ? hid : hid + 32;
    float osum = 0.f, osum2 = 0.f;
#pragma unroll
    for (int m = 0; m < 4; ++m) {
        int xb = m * 16 + kq * 4;
        size_t pixbase = (size_t)(b * 64 + y0) * 64 + xb;
        float4 o4;
#pragma unroll
        for (int r = 0; r < 4; ++r) {
            float ci = acc[m][0][r] + bi;
            float cf = acc[m][1][r] + bff;
            float co = acc[m][2][r] + bo;
            float cg = acc[m][3][r] + bg;
            size_t ca = (pixbase + r) * 64 + hid;
            float c_old = c_ws[ca];
            float si = 1.f / (1.f + __expf(-ci));
            float sf = 1.f / (1.f + __expf(-cf));
            float so = 1.f / (1.f + __expf(-co));
            float c_new = sf * c_old + si * tanh_fast(cg);
            float h = so * tanh_fast(c_new);
            c_ws[ca] = c_new;
            unsigned short hh = f2bf(h);
            unsigned short hl = f2bf(h - bf2f(hh));
            unsigned short* hp = h_out + (pixbase + r) * 128;
            hp[chh] = hh;
            hp[chh + 32] = hl;
            float ov = (h >= 0.f) ? h : NEG_SLOPE * h;
            (&o4.x)[r] = ov;
            osum += ov;
            osum2 += ov * ov;
        }
        *(float4*)(out + (((size_t)(b * TT + t) * 64 + hid) * 64 + y0) * 64 + xb) = o4;
    }
    osum  += __shfl_xor(osum, 16);  osum  += __shfl_xor(osum, 32);
    osum2 += __shfl_xor(osum2, 16); osum2 += __shfl_xor(osum2, 32);
    if (kq == 0) {
        int bid = b * 64 + y0;
        partial[bid * 128 + hid] += osum;
        partial[bid * 128 + 64 + hid] += osum2;
    }
}

__global__ __launch_bounds__(512) void finalize_stats(const float* __restrict__ partial,
                                                      float* __restrict__ stats,
                                                      const float* __restrict__ gamma,
                                                      const float* __restrict__ beta) {
    int idx = threadIdx.x & 127;
    int seg = threadIdx.x >> 7;       // 0..3, each sums 128 of 512 blocks
    float s = 0.f;
    for (int k = seg * 128; k < seg * 128 + 128; ++k) s += partial[k * 128 + idx];
    __shared__ float red[4][128];
    red[seg][idx] = s;
    __syncthreads();
    if (threadIdx.x < 64) {
        int hid = threadIdx.x;
        const float n = (float)((size_t)BB * TT * HH * WW);
        float mean = (red[0][hid] + red[1][hid] + red[2][hid] + red[3][hid]) / n;
        float var  = (red[0][64 + hid] + red[1][64 + hid] + red[2][64 + hid] + red[3][64 + hid]) / n
                     - mean * mean;
        float inv  = rsqrtf(var + EPS);
        float sc   = gamma[hid] * inv;
        stats[hid]      = sc;
        stats[64 + hid] = beta[hid] - mean * sc;
    }
}

__global__ __launch_bounds__(256) void normalize_k(float* __restrict__ out,
                                                   const float* __restrict__ stats) {
    const size_t N = (size_t)BB * TT * HID * HH * WW;
    size_t i = ((size_t)blockIdx.x * blockDim.x + threadIdx.x) * 4;
    size_t stride = (size_t)gridDim.x * blockDim.x * 4;
    for (; i < N; i += stride) {
        int ch = (int)((i >> 12) & (HID - 1));
        float sc = stats[ch], sh = stats[64 + ch];
        float4 v = *(float4*)(out + i);
        v.x = fmaf(v.x, sc, sh);
        v.y = fmaf(v.y, sc, sh);
        v.z = fmaf(v.z, sc, sh);
        v.w = fmaf(v.w, sc, sh);
        *(float4*)(out + i) = v;
    }
}

extern "C" void kernel_launch(void* const* d_in, const int* in_sizes, int n_in,
                              void* d_out, int out_size, void* d_ws, size_t ws_size,
                              hipStream_t stream) {
    const float* x     = (const float*)d_in[0];
    const float* w     = (const float*)d_in[1];
    const float* bias  = (const float*)d_in[2];
    const float* gamma = (const float*)d_in[3];
    const float* beta  = (const float*)d_in[4];
    float* out = (float*)d_out;
    char* wsb = (char*)d_ws;

    unsigned short* xcl  = (unsigned short*)(wsb);                    // 33,554,432 B
    unsigned short* wpkb = (unsigned short*)(wsb + 33554432);         //    442,368 B
    unsigned short* hA   = (unsigned short*)(wsb + 33996800);         //  8,388,608 B
    unsigned short* hB   = (unsigned short*)(wsb + 42385408);         //  8,388,608 B
    float* c_ws          = (float*)(wsb + 50774016);                  //  8,388,608 B
    float* partial       = (float*)(wsb + 59162624);                  // 512*128*4 B
    float* stats         = partial + 512 * 128;                       // 512 B

    hipMemsetAsync(hA, 0, 8388608, stream);
    hipMemsetAsync(c_ws, 0, 8388608, stream);
    hipMemsetAsync(partial, 0, (512 * 128 + 128) * 4, stream);

    x2bf<<<dim3(64, 16, 8), 256, 0, stream>>>(x, xcl);
    pack_wb<<<864, 256, 0, stream>>>(w, wpkb);

    unsigned short* hin = hA;
    unsigned short* hout = hB;
    for (int t = 0; t < TT; ++t) {
        lstm_step<<<dim3(64, 8), 256, 0, stream>>>(xcl, wpkb, bias, hin, hout,
                                                   c_ws, out, partial, t);
        unsigned short* tmp = hin; hin = hout; hout = tmp;
    }
    finalize_stats<<<1, 512, 0, stream>>>(partial, stats, gamma, beta);
    normalize_k<<<8192, 256, 0, stream>>>(out, stats);
}